// Round 3
// baseline (23.927 us; speedup 1.0000x reference)
//
#include <hip/hip_runtime.h>
#include <hip/hip_bf16.h>

#define MM 16      // mixtures
#define DD 128     // visible dims
#define CC 50      // categories
#define BB 32768   // batch
#define DCH 32     // d's per LDS chunk (4 chunks)

// ---------------------------------------------------------------------------
// Kernel 1: one WAVE per (m,d) row; shfl-reduce log_softmax; store bf16
// transposed to [D][C][M] (u32-pair layout [D][C][8]).
// ---------------------------------------------------------------------------
__global__ __launch_bounds__(256) void prep_kernel(
    const float* __restrict__ cate,    // [M][D][C] f32
    const float* __restrict__ mw,      // [M]
    unsigned short* __restrict__ tabw, // [D][C][M] bf16
    float* __restrict__ logw)          // [M]
{
    const int wid  = (blockIdx.x * 256 + threadIdx.x) >> 6;  // 0..2047
    const int lane = threadIdx.x & 63;
    const int m = wid >> 7;        // wid / DD
    const int d = wid & (DD - 1);  // wid % DD

    const float* row = cate + (m * DD + d) * CC;
    float v = (lane < CC) ? row[lane] : -1e30f;

    float mx = v;
    #pragma unroll
    for (int off = 32; off; off >>= 1)
        mx = fmaxf(mx, __shfl_xor(mx, off, 64));
    float e = (lane < CC) ? __expf(v - mx) : 0.f;
    #pragma unroll
    for (int off = 32; off; off >>= 1)
        e += __shfl_xor(e, off, 64);
    float lse = mx + __logf(e);

    if (lane < CC) {
        float lp = v - lse;
        unsigned int bits = __float_as_uint(lp);
        bits += 0x7fffu + ((bits >> 16) & 1u);   // round-to-nearest-even
        tabw[(d * CC + lane) * MM + m] = (unsigned short)(bits >> 16);
    }

    if (wid == 0 && lane < MM) {
        float mw_l = mw[lane];
        float mmx = -1e30f;
        #pragma unroll
        for (int i = 0; i < MM; ++i) mmx = fmaxf(mmx, mw[i]);
        float s = 0.f;
        #pragma unroll
        for (int i = 0; i < MM; ++i) s += __expf(mw[i] - mmx);
        logw[lane] = mw_l - (mmx + __logf(s));
    }
}

// ---------------------------------------------------------------------------
// Kernel 2: LDS-staged gather. 256 blocks x 512 threads; block owns 128 batch
// rows. Table (200 KB bf16, u32-pair layout [D][C][8]) staged in 4 chunks of
// 51.2 KB. Within a row: 4 lanes, lane l owns mixtures 4l..4l+3 read as one
// ds_read_b64 (u32 pair) per d. Random-c bank conflicts average ~4-way
// (rows land in 4 of the 8-bank groups) ~= 1.6x cost, fine.
// ---------------------------------------------------------------------------
__global__ __launch_bounds__(512) void gather_kernel(
    const int* __restrict__ x,            // [B][D] int32
    const unsigned int* __restrict__ tab, // [D][C][8] u32 (= bf16 pairs)
    const float* __restrict__ logw,       // [M]
    float* __restrict__ out)              // [B]
{
    __shared__ __align__(16) unsigned int lds[DCH * CC * 8];  // 51200 B

    const int tid = threadIdx.x;
    const int l   = tid & 3;         // mixture-quad index (m = 4l..4l+3)
    const int r   = tid >> 2;        // 0..127
    const int b   = blockIdx.x * 128 + r;

    const int4* __restrict__ xrow = (const int4*)(x + b * DD);

    float a0 = 0.f, a1 = 0.f, a2 = 0.f, a3 = 0.f;

    #pragma unroll 1
    for (int ch = 0; ch < DD / DCH; ++ch) {
        // ---- stage chunk ch (51200 B) into LDS, float4-vectorized ----
        {
            const float4* __restrict__ src = (const float4*)(tab + ch * (DCH * CC * 8));
            float4* dst = (float4*)lds;
            for (int i = tid; i < DCH * CC * 8 / 4; i += 512)
                dst[i] = src[i];
        }
        __syncthreads();

        // ---- preload this chunk's x values (8 int4 = 32 d's) ----
        int4 xv[DCH / 4];
        #pragma unroll
        for (int j = 0; j < DCH / 4; ++j)
            xv[j] = xrow[ch * (DCH / 4) + j];

        // ---- gather: per d, ds_read_b64 of lane's mixture quad ----
        #pragma unroll
        for (int j = 0; j < DCH / 4; ++j) {
            int cs[4] = { xv[j].x, xv[j].y, xv[j].z, xv[j].w };
            #pragma unroll
            for (int k = 0; k < 4; ++k) {
                int dloc = j * 4 + k;
                const unsigned int* p = &lds[(dloc * CC + cs[k]) * 8 + 2 * l];
                unsigned int u0 = p[0];
                unsigned int u1 = p[1];
                a0 += __uint_as_float(u0 << 16);
                a1 += __uint_as_float(u0 & 0xffff0000u);
                a2 += __uint_as_float(u1 << 16);
                a3 += __uint_as_float(u1 & 0xffff0000u);
            }
        }
        __syncthreads();
    }

    // ---- logsumexp over 16 mixtures: 4 in-lane + 4-lane group reduce ----
    float l0 = a0 + logw[4 * l + 0];
    float l1 = a1 + logw[4 * l + 1];
    float l2 = a2 + logw[4 * l + 2];
    float l3 = a3 + logw[4 * l + 3];

    float mx = fmaxf(fmaxf(l0, l1), fmaxf(l2, l3));
    mx = fmaxf(mx, __shfl_xor(mx, 1, 64));
    mx = fmaxf(mx, __shfl_xor(mx, 2, 64));
    float e = __expf(l0 - mx) + __expf(l1 - mx) + __expf(l2 - mx) + __expf(l3 - mx);
    e += __shfl_xor(e, 1, 64);
    e += __shfl_xor(e, 2, 64);

    if (l == 0) out[b] = mx + __logf(e);
}

extern "C" void kernel_launch(void* const* d_in, const int* in_sizes, int n_in,
                              void* d_out, int out_size, void* d_ws, size_t ws_size,
                              hipStream_t stream) {
    const int*   x    = (const int*)d_in[0];     // [B][D]
    const float* mw   = (const float*)d_in[1];   // [M]
    const float* cate = (const float*)d_in[2];   // [M][D][C]
    float* out = (float*)d_out;

    unsigned short* tabw = (unsigned short*)d_ws;           // D*C*M bf16 = 204800 B
    float* logw = (float*)((char*)d_ws + (size_t)DD * CC * MM * sizeof(unsigned short));

    // prep: one wave per (m,d) row -> 2048 waves (512 blocks x 4 waves)
    prep_kernel<<<(MM * DD) / 4, 256, 0, stream>>>(cate, mw, tabw, logw);

    // gather: 128 batch rows per 512-thread block, table staged via LDS
    gather_kernel<<<BB / 128, 512, 0, stream>>>(x, (const unsigned int*)tabw, logw, out);
}